// Round 7
// baseline (4383.569 us; speedup 1.0000x reference)
//
#include <hip/hip_runtime.h>

typedef __attribute__((ext_vector_type(4))) float f32x4;
typedef __attribute__((ext_vector_type(8))) short s16x8;

#define MFMA16(a, b, c) __builtin_amdgcn_mfma_f32_16x16x32_bf16((a), (b), (c), 0, 0, 0)

__device__ __forceinline__ float hsig(float x) {
    return fminf(fmaxf(0.2f * x + 0.5f, 0.0f), 1.0f);
}

__device__ __forceinline__ unsigned short bf16rne(float v) {
    unsigned u = __float_as_uint(v);
    u += 0x7FFFu + ((u >> 16) & 1u);
    return (unsigned short)(u >> 16);
}
__device__ __forceinline__ void split2(float v, unsigned short& h, unsigned short& l) {
    h = bf16rne(v);
    float hv = __uint_as_float((unsigned)h << 16);
    l = bf16rne(v - hv);
}

// ---- weight prep: reorder to MFMA B-fragment order ----
// Bw layout: [ks][ hi: nfrag(16) x lane(64) x 8 | lo: same ]  (16384 ushorts per ks)
template<int KHW, int CX, int NS>
__global__ __launch_bounds__(256)
void prep_w(const float* __restrict__ Kw, const float* __restrict__ Rw,
            unsigned short* __restrict__ Bw)
{
    int gid = blockIdx.x * 256 + threadIdx.x;
    if (gid >= NS * 1024) return;
    int lane  = gid & 63;
    int nfrag = (gid >> 6) & 15;
    int ks    = gid >> 10;
    int n  = nfrag * 16 + (lane & 15);
    int kl = (lane >> 4) * 8;
    constexpr int KX = KHW * CX;
    s16x8 vh, vl;
#pragma unroll
    for (int j = 0; j < 8; ++j) {
        int kg = ks * 32 + kl + j;
        float w = (kg < KX) ? Kw[(long)kg * 256 + n]
                            : Rw[(long)(kg - KX) * 256 + n];
        unsigned short h, l;
        split2(w, h, l);
        vh[j] = (short)h;
        vl[j] = (short)l;
    }
    unsigned short* o = Bw + (long)ks * 16384 + nfrag * 512 + lane * 8;
    *(s16x8*)o = vh;
    *(s16x8*)(o + 8192) = vl;
}

// ---- stage zero-padded tile as bf16 hi/lo planes, chunk-major [c/8][pixel][8] ----
template<int C, int TS, int PAD, int CST>
__device__ __forceinline__ void stage_split(const float* __restrict__ gp,
                                            unsigned short* __restrict__ hi_,
                                            unsigned short* __restrict__ lo_,
                                            int ty0, int tx0, int tid)
{
    constexpr int CH = C / 8;
    constexpr int NP = TS * TS;
    for (int i = tid; i < NP * CH; i += 512) {
        int ch = i % CH;
        int p  = i / CH;
        int py = p / TS, px = p % TS;
        int iy = ty0 + py - PAD, ix = tx0 + px - PAD;
        float v[8];
        if (iy >= 0 && iy < 64 && ix >= 0 && ix < 64) {
            const float* s = gp + ((long)(iy * 64 + ix)) * C + ch * 8;
            f32x4 a = *(const f32x4*)s;
            f32x4 b = *(const f32x4*)(s + 4);
#pragma unroll
            for (int j = 0; j < 4; ++j) { v[j] = a[j]; v[4 + j] = b[j]; }
        } else {
#pragma unroll
            for (int j = 0; j < 8; ++j) v[j] = 0.0f;
        }
        s16x8 vh, vl;
#pragma unroll
        for (int j = 0; j < 8; ++j) {
            unsigned short h, l;
            split2(v[j], h, l);
            vh[j] = (short)h;
            vl[j] = (short)l;
        }
        *(s16x8*)(hi_ + ch * CST + p * 8) = vh;
        *(s16x8*)(lo_ + ch * CST + p * 8) = vl;
    }
}

// ---- fused ConvLSTM step body (r4 structure), callable per layer ----
// M=64 pixels (8x8 tile), N=256 gate-channels, K = KHW*(CX+64).
// 8 waves = 2 K-groups x 4 N-quarters; K-group partials summed in z-exchange.
template<int KW, int CX, int TS, int NS, int XS>
__device__ __forceinline__ void lstm_body(
    unsigned short* __restrict__ smem,
    const float* __restrict__ xin, long xbstride,
    const float* __restrict__ hin,
    const unsigned short* __restrict__ Bg,
    const float* __restrict__ bias,
    float* __restrict__ c_buf,
    float* __restrict__ h_out,
    float* __restrict__ y_out, long ybstride,
    int b)
{
    constexpr int PAD = KW / 2;
    constexpr int NP  = TS * TS;
    constexpr int CHX = CX / 8;
    constexpr int CST = NP * 8;              // chunk stride (ushorts)
    constexpr int XPLANE = CHX * CST;
    constexpr int HPLANE = 8 * CST;
    constexpr int ZST = 260;                 // z row stride (f32)
    constexpr int ZPL = 32 * ZST;            // per-K-group plane (f32)
    constexpr int SPLIT = (NS + 1) / 2;      // k-group boundary

    unsigned short* sxh = smem;
    unsigned short* sxl = sxh + XPLANE;
    unsigned short* shh = sxl + XPLANE;
    unsigned short* shl = shh + HPLANE;

    const int tid  = threadIdx.x;
    const int lane = tid & 63, wid = tid >> 6;
    const int nq = wid & 3;                  // N-quarter: columns [64nq, 64nq+64)
    const int kg = wid >> 2;                 // K-group
    const int ty0 = blockIdx.y * 8, tx0 = blockIdx.x * 8;

    const int ks0 = kg ? SPLIT : 0;
    const int ks1 = kg ? NS : SPLIT;

    const unsigned short* bp = Bg + (long)ks0 * 16384 + (nq * 4) * 512 + lane * 8;

    s16x8 Bh[2][4], Bl[2][4];
#define LOADB(BI, Q)                                             \
    {                                                            \
        const unsigned short* q_ = (Q);                          \
        _Pragma("unroll")                                        \
        for (int nf = 0; nf < 4; ++nf) {                         \
            Bh[BI][nf] = *(const s16x8*)(q_ + nf * 512);         \
            Bl[BI][nf] = *(const s16x8*)(q_ + 8192 + nf * 512);  \
        }                                                        \
    }

    LOADB(0, bp);             // first k-step, overlaps with staging

    stage_split<CX, TS, PAD, CST>(xin + (long)b * xbstride, sxh, sxl, ty0, tx0, tid);
    stage_split<64, TS, PAD, CST>(hin + (long)b * 4096 * 64, shh, shl, ty0, tx0, tid);
    __syncthreads();

    f32x4 acc[4][4];
#pragma unroll
    for (int mf = 0; mf < 4; ++mf)
#pragma unroll
        for (int nf = 0; nf < 4; ++nf)
#pragma unroll
            for (int q = 0; q < 4; ++q) acc[mf][nf][q] = 0.0f;

    const int pb  = lane & 15;
    const int kq  = (lane >> 4) * CST;
    const int av0 = (((pb      >> 3) * TS) + (pb      & 7)) * 8 + kq;
    const int av1 = ((((pb+16) >> 3) * TS) + ((pb+16) & 7)) * 8 + kq;
    const int av2 = ((((pb+32) >> 3) * TS) + ((pb+32) & 7)) * 8 + kq;
    const int av3 = ((((pb+48) >> 3) * TS) + ((pb+48) & 7)) * 8 + kq;

    s16x8 Ar[2][8];  // [buf][ mf0..3 hi | mf0..3 lo ]
#define LOADA(AI, KS)                                                    \
    {                                                                    \
        int ksv_ = (KS);                                                 \
        int tap_, cb8_;                                                  \
        const unsigned short *ph_, *pl_;                                 \
        if (ksv_ < XS) {                                                 \
            if (CX == 32) { tap_ = ksv_; cb8_ = 0; }                     \
            else { tap_ = ksv_ >> 1; cb8_ = (ksv_ & 1) * 4; }            \
            ph_ = sxh; pl_ = sxl;                                        \
        } else {                                                         \
            int kk_ = ksv_ - XS;                                         \
            tap_ = kk_ >> 1; cb8_ = (kk_ & 1) * 4;                       \
            ph_ = shh; pl_ = shl;                                        \
        }                                                                \
        int kh_ = tap_ / KW, kw_ = tap_ - kh_ * KW;                      \
        int so_ = cb8_ * CST + (kh_ * TS + kw_) * 8;                     \
        Ar[AI][0] = *(const s16x8*)(ph_ + so_ + av0);                    \
        Ar[AI][1] = *(const s16x8*)(ph_ + so_ + av1);                    \
        Ar[AI][2] = *(const s16x8*)(ph_ + so_ + av2);                    \
        Ar[AI][3] = *(const s16x8*)(ph_ + so_ + av3);                    \
        Ar[AI][4] = *(const s16x8*)(pl_ + so_ + av0);                    \
        Ar[AI][5] = *(const s16x8*)(pl_ + so_ + av1);                    \
        Ar[AI][6] = *(const s16x8*)(pl_ + so_ + av2);                    \
        Ar[AI][7] = *(const s16x8*)(pl_ + so_ + av3);                    \
    }

    // 3 passes: ah*bh, al*bh, ah*bl ; 16 independent acc chains.
#define MM(AI, BI)                                                        \
    {                                                                     \
        __builtin_amdgcn_s_setprio(1);                                    \
        _Pragma("unroll")                                                 \
        for (int nf = 0; nf < 4; ++nf)                                    \
        {                                                                 \
            _Pragma("unroll")                                             \
            for (int mf = 0; mf < 4; ++mf)                                \
                acc[mf][nf] = MFMA16(Ar[AI][mf], Bh[BI][nf], acc[mf][nf]);\
        }                                                                 \
        _Pragma("unroll")                                                 \
        for (int nf = 0; nf < 4; ++nf)                                    \
        {                                                                 \
            _Pragma("unroll")                                             \
            for (int mf = 0; mf < 4; ++mf)                                \
                acc[mf][nf] = MFMA16(Ar[AI][4+mf], Bh[BI][nf], acc[mf][nf]);\
        }                                                                 \
        _Pragma("unroll")                                                 \
        for (int nf = 0; nf < 4; ++nf)                                    \
        {                                                                 \
            _Pragma("unroll")                                             \
            for (int mf = 0; mf < 4; ++mf)                                \
                acc[mf][nf] = MFMA16(Ar[AI][mf], Bl[BI][nf], acc[mf][nf]);\
        }                                                                 \
        __builtin_amdgcn_s_setprio(0);                                    \
    }

    LOADA(0, ks0);

    const unsigned short* bq = bp;
    int ks = ks0;
#pragma unroll 1
    for (; ks + 1 < ks1; ks += 2, bq += 32768) {
        LOADB(1, bq + 16384);
        LOADA(1, ks + 1);
        MM(0, 0);
        if (ks + 2 < ks1) {
            LOADB(0, bq + 32768);
            LOADA(0, ks + 2);
        }
        MM(1, 1);
    }
    if (ks < ks1) MM(0, 0);   // odd-count tail (buf0 holds ks)

    // ---- z exchange: per-K-group planes, 2 rounds of 32 pixels ----
    __syncthreads();
    float* zl = (float*)smem;  // [kg][32][ZST] f32 = 66.5 KB overlay
    const int f = tid & 63;
    const float bi = bias[f], bfr = bias[64 + f], bg = bias[128 + f], bo = bias[192 + f];

#define ZROUND(RR)                                                            \
    {                                                                         \
        _Pragma("unroll")                                                     \
        for (int mi = 0; mi < 2; ++mi)                                        \
        {                                                                     \
            _Pragma("unroll")                                                 \
            for (int nf = 0; nf < 4; ++nf)                                    \
            {                                                                 \
                _Pragma("unroll")                                             \
                for (int q = 0; q < 4; ++q) {                                 \
                    int pl_ = mi * 16 + (lane >> 4) * 4 + q;                  \
                    int c   = nq * 64 + nf * 16 + (lane & 15);                \
                    zl[kg * ZPL + pl_ * ZST + (c & 63) * 4 + (c >> 6)] =      \
                        acc[2 * (RR) + mi][nf][q];                            \
                }                                                             \
            }                                                                 \
        }                                                                     \
        __syncthreads();                                                      \
        _Pragma("unroll")                                                     \
        for (int j = 0; j < 4; ++j) {                                         \
            int pl_ = (tid >> 6) + j * 8;                                     \
            int p   = (RR) * 32 + pl_;                                        \
            f32x4 za = *(const f32x4*)(zl + pl_ * ZST + f * 4);               \
            f32x4 zb = *(const f32x4*)(zl + ZPL + pl_ * ZST + f * 4);         \
            float zi = za[0] + zb[0] + bi, zf = za[1] + zb[1] + bfr;          \
            float zg = za[2] + zb[2] + bg, zo = za[3] + zb[3] + bo;           \
            int y = ty0 + (p >> 3), x = tx0 + (p & 7);                        \
            long o = ((long)((b * 64 + y) * 64 + x)) * 64 + f;                \
            float cv = c_buf[o];                                              \
            float cn = hsig(zf) * cv + hsig(zi) * tanhf(zg);                  \
            c_buf[o] = cn;                                                    \
            float hn = hsig(zo) * tanhf(cn);                                  \
            h_out[o] = hn;                                                    \
            y_out[(long)b * ybstride + ((long)(y * 64 + x)) * 64 + f] =       \
                fmaxf(hn, 0.0f);                                              \
        }                                                                     \
        __syncthreads();                                                      \
    }

    ZROUND(0)
    ZROUND(1)

#undef LOADB
#undef LOADA
#undef MM
#undef ZROUND
}

// ---- fused dual-layer launch: z<4 -> layer1 step t, z>=4 -> layer2 step t-1 ----
// The two block kinds are data-independent within a launch and co-resident
// (2 blocks/CU, 4 waves/SIMD): one block's MFMA covers the other's waits.
// mode: 0 = L1 only (grid.z=4), 1 = L2 only (grid.z=4), 2 = both (grid.z=8).
__global__ __launch_bounds__(512, 4)
void lstm_fused(
    const float* __restrict__ x1, const float* __restrict__ h1in,
    const unsigned short* __restrict__ B1g, const float* __restrict__ bias1,
    float* __restrict__ c1, float* __restrict__ h1out, float* __restrict__ y1out,
    const float* __restrict__ x2, const float* __restrict__ h2in,
    const unsigned short* __restrict__ B2g, const float* __restrict__ bias2,
    float* __restrict__ c2, float* __restrict__ h2out, float* __restrict__ y2out,
    int mode)
{
    __shared__ __align__(16) unsigned short smem[33280];  // 66.5 KB
    const int z = blockIdx.z;
    const int b = z & 3;
    const bool doL2 = (mode == 1) || (z >= 4);
    if (!doL2) {
        lstm_body<5, 32, 12, 75, 25>(smem, x1, (long)8 * 4096 * 32, h1in,
                                     B1g, bias1, c1, h1out,
                                     y1out, (long)8 * 4096 * 64, b);
    } else {
        lstm_body<3, 64, 10, 36, 18>(smem, x2, (long)8 * 4096 * 64, h2in,
                                     B2g, bias2, c2, h2out,
                                     y2out, (long)8 * 4096 * 64, b);
    }
}

extern "C" void kernel_launch(void* const* d_in, const int* in_sizes, int n_in,
                              void* d_out, int out_size, void* d_ws, size_t ws_size,
                              hipStream_t stream)
{
    const float* x  = (const float*)d_in[0];
    const float* K1 = (const float*)d_in[1];
    const float* R1 = (const float*)d_in[2];
    const float* b1 = (const float*)d_in[3];
    const float* K2 = (const float*)d_in[4];
    const float* R2 = (const float*)d_in[5];
    const float* b2 = (const float*)d_in[6];
    float* out = (float*)d_out;

    const long HW   = 4096;
    const long SZ_S = HW * 64 * 4;      // 1,048,576 floats per [B,H,W,64]
    const long SZ_Y = SZ_S * 8;

    float* ws  = (float*)d_ws;
    float* y1  = ws;                    // 8,388,608 f32 ([B][T][HW][64])
    float* h1a = y1 + SZ_Y;
    float* h1b = h1a + SZ_S;
    float* h2a = h1b + SZ_S;
    float* h2b = h2a + SZ_S;
    float* c1  = h2b + SZ_S;
    float* c2  = c1 + SZ_S;
    unsigned short* B1 = (unsigned short*)(c2 + SZ_S);   // 75*16384 ushorts
    unsigned short* B2 = B1 + (long)75 * 16384;          // 36*16384 ushorts

    // weight prep
    prep_w<25, 32, 75><<<300, 256, 0, stream>>>(K1, R1, B1);
    prep_w<9,  64, 36><<<144, 256, 0, stream>>>(K2, R2, B2);

    hipMemsetAsync(h1a, 0, (size_t)SZ_S * sizeof(float), stream);
    hipMemsetAsync(c1,  0, (size_t)SZ_S * sizeof(float), stream);
    hipMemsetAsync(h2a, 0, (size_t)SZ_S * sizeof(float), stream);
    hipMemsetAsync(c2,  0, (size_t)SZ_S * sizeof(float), stream);

    float* hp1 = h1a; float* hn1 = h1b;
    float* hp2 = h2a; float* hn2 = h2b;

    for (int t = 0; t <= 8; ++t) {
        const int mode = (t == 0) ? 0 : (t == 8) ? 1 : 2;
        const int t1  = (t <= 7) ? t : 7;       // L1 timestep (unused at t=8)
        const int tm1 = (t >= 1) ? t - 1 : 0;   // L2 timestep (unused at t=0)
        dim3 grid(8, 8, mode == 2 ? 8 : 4);
        lstm_fused<<<grid, 512, 0, stream>>>(
            x  + (long)t1 * HW * 32,  hp1, B1, b1, c1, hn1,
            y1 + (long)t1 * HW * 64,
            y1 + (long)tm1 * HW * 64, hp2, B2, b2, c2, hn2,
            out + (long)tm1 * HW * 64,
            mode);
        if (mode != 1) { float* tmp = hp1; hp1 = hn1; hn1 = tmp; }
        if (mode != 0) { float* tmp = hp2; hp2 = hn2; hn2 = tmp; }
    }
}

// Round 8
// 634.077 us; speedup vs baseline: 6.9133x; 6.9133x over previous
//
#include <hip/hip_runtime.h>

typedef __attribute__((ext_vector_type(4))) float f32x4;
typedef __attribute__((ext_vector_type(8))) short s16x8;

#define MFMA16(a, b, c) __builtin_amdgcn_mfma_f32_16x16x32_bf16((a), (b), (c), 0, 0, 0)

__device__ __forceinline__ float hsig(float x) {
    return fminf(fmaxf(0.2f * x + 0.5f, 0.0f), 1.0f);
}

__device__ __forceinline__ unsigned short bf16rne(float v) {
    unsigned u = __float_as_uint(v);
    u += 0x7FFFu + ((u >> 16) & 1u);
    return (unsigned short)(u >> 16);
}
__device__ __forceinline__ void split2(float v, unsigned short& h, unsigned short& l) {
    h = bf16rne(v);
    float hv = __uint_as_float((unsigned)h << 16);
    l = bf16rne(v - hv);
}

// ---- weight prep: reorder to MFMA B-fragment order ----
// Bw layout: [ks][ hi: nfrag(16) x lane(64) x 8 | lo: same ]  (16384 ushorts per ks)
template<int KHW, int CX, int NS>
__global__ __launch_bounds__(256)
void prep_w(const float* __restrict__ Kw, const float* __restrict__ Rw,
            unsigned short* __restrict__ Bw)
{
    int gid = blockIdx.x * 256 + threadIdx.x;
    if (gid >= NS * 1024) return;
    int lane  = gid & 63;
    int nfrag = (gid >> 6) & 15;
    int ks    = gid >> 10;
    int n  = nfrag * 16 + (lane & 15);
    int kl = (lane >> 4) * 8;
    constexpr int KX = KHW * CX;
    s16x8 vh, vl;
#pragma unroll
    for (int j = 0; j < 8; ++j) {
        int kg = ks * 32 + kl + j;
        float w = (kg < KX) ? Kw[(long)kg * 256 + n]
                            : Rw[(long)(kg - KX) * 256 + n];
        unsigned short h, l;
        split2(w, h, l);
        vh[j] = (short)h;
        vl[j] = (short)l;
    }
    unsigned short* o = Bw + (long)ks * 16384 + nfrag * 512 + lane * 8;
    *(s16x8*)o = vh;
    *(s16x8*)(o + 8192) = vl;
}

// ---- stage zero-padded tile as bf16 hi/lo planes, chunk-major [c/8][pixel][8] ----
template<int C, int TS, int PAD, int CST>
__device__ __forceinline__ void stage_split(const float* __restrict__ gp,
                                            unsigned short* __restrict__ hi_,
                                            unsigned short* __restrict__ lo_,
                                            int ty0, int tx0, int tid)
{
    constexpr int CH = C / 8;
    constexpr int NP = TS * TS;
    for (int i = tid; i < NP * CH; i += 512) {
        int ch = i % CH;
        int p  = i / CH;
        int py = p / TS, px = p % TS;
        int iy = ty0 + py - PAD, ix = tx0 + px - PAD;
        float v[8];
        if (iy >= 0 && iy < 64 && ix >= 0 && ix < 64) {
            const float* s = gp + ((long)(iy * 64 + ix)) * C + ch * 8;
            f32x4 a = *(const f32x4*)s;
            f32x4 b = *(const f32x4*)(s + 4);
#pragma unroll
            for (int j = 0; j < 4; ++j) { v[j] = a[j]; v[4 + j] = b[j]; }
        } else {
#pragma unroll
            for (int j = 0; j < 8; ++j) v[j] = 0.0f;
        }
        s16x8 vh, vl;
#pragma unroll
        for (int j = 0; j < 8; ++j) {
            unsigned short h, l;
            split2(v[j], h, l);
            vh[j] = (short)h;
            vl[j] = (short)l;
        }
        *(s16x8*)(hi_ + ch * CST + p * 8) = vh;
        *(s16x8*)(lo_ + ch * CST + p * 8) = vl;
    }
}

// ---- fused ConvLSTM step body (r4 structure, reduced register pressure) ----
// 8 waves = 2 K-groups x 4 N-quarters; K-group partials summed in z-exchange.
// A single-buffered (r2: depth is free), Bh 2-deep (L2 latency), Bl JIT
// (consumed 32 MFMAs after issue). Goal: emitted VGPR <= 128 so two blocks
// (one per layer) co-reside per CU -> 4 waves/SIMD.
template<int KW, int CX, int TS, int NS, int XS>
__device__ __forceinline__ void lstm_body(
    unsigned short* __restrict__ smem,
    const float* __restrict__ xin, long xbstride,
    const float* __restrict__ hin,
    const unsigned short* __restrict__ Bg,
    const float* __restrict__ bias,
    float* __restrict__ c_buf,
    float* __restrict__ h_out,
    float* __restrict__ y_out, long ybstride,
    int b)
{
    constexpr int PAD = KW / 2;
    constexpr int NP  = TS * TS;
    constexpr int CHX = CX / 8;
    constexpr int CST = NP * 8;              // chunk stride (ushorts)
    constexpr int XPLANE = CHX * CST;
    constexpr int HPLANE = 8 * CST;
    constexpr int ZST = 260;                 // z row stride (f32)
    constexpr int ZPL = 32 * ZST;            // per-K-group plane (f32)
    constexpr int SPLIT = (NS + 1) / 2;      // k-group boundary

    unsigned short* sxh = smem;
    unsigned short* sxl = sxh + XPLANE;
    unsigned short* shh = sxl + XPLANE;
    unsigned short* shl = shh + HPLANE;

    const int tid  = threadIdx.x;
    const int lane = tid & 63, wid = tid >> 6;
    const int nq = wid & 3;                  // N-quarter: columns [64nq, 64nq+64)
    const int kg = wid >> 2;                 // K-group
    const int ty0 = blockIdx.y * 8, tx0 = blockIdx.x * 8;

    const int ks0 = kg ? SPLIT : 0;
    const int ks1 = kg ? NS : SPLIT;

    const unsigned short* bp = Bg + (long)ks0 * 16384 + (nq * 4) * 512 + lane * 8;

    s16x8 Bh[2][4];   // 2-deep prefetch (hi plane only)
    s16x8 Bl[4];      // just-in-time (lo plane)
#define LOADBH(BI, Q)                                            \
    {                                                            \
        const unsigned short* q_ = (Q);                          \
        _Pragma("unroll")                                        \
        for (int nf = 0; nf < 4; ++nf)                           \
            Bh[BI][nf] = *(const s16x8*)(q_ + nf * 512);         \
    }
#define LOADBL(Q)                                                \
    {                                                            \
        const unsigned short* q_ = (Q);                          \
        _Pragma("unroll")                                        \
        for (int nf = 0; nf < 4; ++nf)                           \
            Bl[nf] = *(const s16x8*)(q_ + 8192 + nf * 512);      \
    }

    LOADBH(0, bp);            // first k-step, overlaps with staging

    stage_split<CX, TS, PAD, CST>(xin + (long)b * xbstride, sxh, sxl, ty0, tx0, tid);
    stage_split<64, TS, PAD, CST>(hin + (long)b * 4096 * 64, shh, shl, ty0, tx0, tid);
    __syncthreads();

    f32x4 acc[4][4];
#pragma unroll
    for (int mf = 0; mf < 4; ++mf)
#pragma unroll
        for (int nf = 0; nf < 4; ++nf)
#pragma unroll
            for (int q = 0; q < 4; ++q) acc[mf][nf][q] = 0.0f;

    const int pb  = lane & 15;
    const int kq  = (lane >> 4) * CST;
    const int av0 = (((pb      >> 3) * TS) + (pb      & 7)) * 8 + kq;
    const int av1 = ((((pb+16) >> 3) * TS) + ((pb+16) & 7)) * 8 + kq;
    const int av2 = ((((pb+32) >> 3) * TS) + ((pb+32) & 7)) * 8 + kq;
    const int av3 = ((((pb+48) >> 3) * TS) + ((pb+48) & 7)) * 8 + kq;

    s16x8 Ar[8];  // single buffer: mf0..3 hi | mf0..3 lo
#define LOADA(KS)                                                        \
    {                                                                    \
        int ksv_ = (KS);                                                 \
        int tap_, cb8_;                                                  \
        const unsigned short *ph_, *pl_;                                 \
        if (ksv_ < XS) {                                                 \
            if (CX == 32) { tap_ = ksv_; cb8_ = 0; }                     \
            else { tap_ = ksv_ >> 1; cb8_ = (ksv_ & 1) * 4; }            \
            ph_ = sxh; pl_ = sxl;                                        \
        } else {                                                         \
            int kk_ = ksv_ - XS;                                         \
            tap_ = kk_ >> 1; cb8_ = (kk_ & 1) * 4;                       \
            ph_ = shh; pl_ = shl;                                        \
        }                                                                \
        int kh_ = tap_ / KW, kw_ = tap_ - kh_ * KW;                      \
        int so_ = cb8_ * CST + (kh_ * TS + kw_) * 8;                     \
        Ar[0] = *(const s16x8*)(ph_ + so_ + av0);                        \
        Ar[1] = *(const s16x8*)(ph_ + so_ + av1);                        \
        Ar[2] = *(const s16x8*)(ph_ + so_ + av2);                        \
        Ar[3] = *(const s16x8*)(ph_ + so_ + av3);                        \
        Ar[4] = *(const s16x8*)(pl_ + so_ + av0);                        \
        Ar[5] = *(const s16x8*)(pl_ + so_ + av1);                        \
        Ar[6] = *(const s16x8*)(pl_ + so_ + av2);                        \
        Ar[7] = *(const s16x8*)(pl_ + so_ + av3);                        \
    }

    // 3 passes: ah*bh, al*bh, ah*bl ; 16 independent acc chains.
    // Q = base of this k-step's B block (for the JIT Bl load).
#define MM(BI, Q)                                                         \
    {                                                                     \
        LOADBL(Q);                                                        \
        __builtin_amdgcn_s_setprio(1);                                    \
        _Pragma("unroll")                                                 \
        for (int nf = 0; nf < 4; ++nf)                                    \
        {                                                                 \
            _Pragma("unroll")                                             \
            for (int mf = 0; mf < 4; ++mf)                                \
                acc[mf][nf] = MFMA16(Ar[mf], Bh[BI][nf], acc[mf][nf]);    \
        }                                                                 \
        _Pragma("unroll")                                                 \
        for (int nf = 0; nf < 4; ++nf)                                    \
        {                                                                 \
            _Pragma("unroll")                                             \
            for (int mf = 0; mf < 4; ++mf)                                \
                acc[mf][nf] = MFMA16(Ar[4 + mf], Bh[BI][nf], acc[mf][nf]);\
        }                                                                 \
        _Pragma("unroll")                                                 \
        for (int nf = 0; nf < 4; ++nf)                                    \
        {                                                                 \
            _Pragma("unroll")                                             \
            for (int mf = 0; mf < 4; ++mf)                                \
                acc[mf][nf] = MFMA16(Ar[mf], Bl[nf], acc[mf][nf]);        \
        }                                                                 \
        __builtin_amdgcn_s_setprio(0);                                    \
    }

    const unsigned short* bq = bp;
    int ks = ks0;
#pragma unroll 1
    for (; ks + 1 < ks1; ks += 2, bq += 32768) {
        LOADBH(1, bq + 16384);
        LOADA(ks);
        MM(0, bq);
        if (ks + 2 < ks1) LOADBH(0, bq + 32768);
        LOADA(ks + 1);
        MM(1, bq + 16384);
    }
    if (ks < ks1) {               // odd-count tail
        LOADA(ks);
        MM(0, bq);
    }

    // ---- z exchange: per-K-group planes, 2 rounds of 32 pixels ----
    __syncthreads();
    float* zl = (float*)smem;  // [kg][32][ZST] f32 = 66.5 KB overlay
    const int f = tid & 63;
    const float bi = bias[f], bfr = bias[64 + f], bg = bias[128 + f], bo = bias[192 + f];

#define ZROUND(RR)                                                            \
    {                                                                         \
        _Pragma("unroll")                                                     \
        for (int mi = 0; mi < 2; ++mi)                                        \
        {                                                                     \
            _Pragma("unroll")                                                 \
            for (int nf = 0; nf < 4; ++nf)                                    \
            {                                                                 \
                _Pragma("unroll")                                             \
                for (int q = 0; q < 4; ++q) {                                 \
                    int pl_ = mi * 16 + (lane >> 4) * 4 + q;                  \
                    int c   = nq * 64 + nf * 16 + (lane & 15);                \
                    zl[kg * ZPL + pl_ * ZST + (c & 63) * 4 + (c >> 6)] =      \
                        acc[2 * (RR) + mi][nf][q];                            \
                }                                                             \
            }                                                                 \
        }                                                                     \
        __syncthreads();                                                      \
        _Pragma("unroll")                                                     \
        for (int j = 0; j < 4; ++j) {                                         \
            int pl_ = (tid >> 6) + j * 8;                                     \
            int p   = (RR) * 32 + pl_;                                        \
            f32x4 za = *(const f32x4*)(zl + pl_ * ZST + f * 4);               \
            f32x4 zb = *(const f32x4*)(zl + ZPL + pl_ * ZST + f * 4);         \
            float zi = za[0] + zb[0] + bi, zf = za[1] + zb[1] + bfr;          \
            float zg = za[2] + zb[2] + bg, zo = za[3] + zb[3] + bo;           \
            int y = ty0 + (p >> 3), x = tx0 + (p & 7);                        \
            long o = ((long)((b * 64 + y) * 64 + x)) * 64 + f;                \
            float cv = c_buf[o];                                              \
            float cn = hsig(zf) * cv + hsig(zi) * tanhf(zg);                  \
            c_buf[o] = cn;                                                    \
            float hn = hsig(zo) * tanhf(cn);                                  \
            h_out[o] = hn;                                                    \
            y_out[(long)b * ybstride + ((long)(y * 64 + x)) * 64 + f] =       \
                fmaxf(hn, 0.0f);                                              \
        }                                                                     \
        __syncthreads();                                                      \
    }

    ZROUND(0)
    ZROUND(1)

#undef LOADBH
#undef LOADBL
#undef LOADA
#undef MM
#undef ZROUND
}

// ---- fused dual-layer launch: z<4 -> layer1 step t, z>=4 -> layer2 step t-1 ----
// Data-independent within a launch; blocks of the two kinds co-reside
// (2 blocks/CU, 4 waves/SIMD) IF emitted VGPR <= 128 -- hence
// __launch_bounds__(512, 2): no forced cap (r7's cap caused spill disaster);
// occupancy comes from actual register count.
__global__ __launch_bounds__(512, 2)
void lstm_fused(
    const float* __restrict__ x1, const float* __restrict__ h1in,
    const unsigned short* __restrict__ B1g, const float* __restrict__ bias1,
    float* __restrict__ c1, float* __restrict__ h1out, float* __restrict__ y1out,
    const float* __restrict__ x2, const float* __restrict__ h2in,
    const unsigned short* __restrict__ B2g, const float* __restrict__ bias2,
    float* __restrict__ c2, float* __restrict__ h2out, float* __restrict__ y2out,
    int mode)
{
    __shared__ __align__(16) unsigned short smem[33280];  // 66.5 KB
    const int z = blockIdx.z;
    const int b = z & 3;
    const bool doL2 = (mode == 1) || (z >= 4);
    if (!doL2) {
        lstm_body<5, 32, 12, 75, 25>(smem, x1, (long)8 * 4096 * 32, h1in,
                                     B1g, bias1, c1, h1out,
                                     y1out, (long)8 * 4096 * 64, b);
    } else {
        lstm_body<3, 64, 10, 36, 18>(smem, x2, (long)8 * 4096 * 64, h2in,
                                     B2g, bias2, c2, h2out,
                                     y2out, (long)8 * 4096 * 64, b);
    }
}

extern "C" void kernel_launch(void* const* d_in, const int* in_sizes, int n_in,
                              void* d_out, int out_size, void* d_ws, size_t ws_size,
                              hipStream_t stream)
{
    const float* x  = (const float*)d_in[0];
    const float* K1 = (const float*)d_in[1];
    const float* R1 = (const float*)d_in[2];
    const float* b1 = (const float*)d_in[3];
    const float* K2 = (const float*)d_in[4];
    const float* R2 = (const float*)d_in[5];
    const float* b2 = (const float*)d_in[6];
    float* out = (float*)d_out;

    const long HW   = 4096;
    const long SZ_S = HW * 64 * 4;      // 1,048,576 floats per [B,H,W,64]
    const long SZ_Y = SZ_S * 8;

    float* ws  = (float*)d_ws;
    float* y1  = ws;                    // 8,388,608 f32 ([B][T][HW][64])
    float* h1a = y1 + SZ_Y;
    float* h1b = h1a + SZ_S;
    float* h2a = h1b + SZ_S;
    float* h2b = h2a + SZ_S;
    float* c1  = h2b + SZ_S;
    float* c2  = c1 + SZ_S;
    unsigned short* B1 = (unsigned short*)(c2 + SZ_S);   // 75*16384 ushorts
    unsigned short* B2 = B1 + (long)75 * 16384;          // 36*16384 ushorts

    // weight prep
    prep_w<25, 32, 75><<<300, 256, 0, stream>>>(K1, R1, B1);
    prep_w<9,  64, 36><<<144, 256, 0, stream>>>(K2, R2, B2);

    hipMemsetAsync(h1a, 0, (size_t)SZ_S * sizeof(float), stream);
    hipMemsetAsync(c1,  0, (size_t)SZ_S * sizeof(float), stream);
    hipMemsetAsync(h2a, 0, (size_t)SZ_S * sizeof(float), stream);
    hipMemsetAsync(c2,  0, (size_t)SZ_S * sizeof(float), stream);

    float* hp1 = h1a; float* hn1 = h1b;
    float* hp2 = h2a; float* hn2 = h2b;

    for (int t = 0; t <= 8; ++t) {
        const int mode = (t == 0) ? 0 : (t == 8) ? 1 : 2;
        const int t1  = (t <= 7) ? t : 7;       // L1 timestep (unused at t=8)
        const int tm1 = (t >= 1) ? t - 1 : 0;   // L2 timestep (unused at t=0)
        dim3 grid(8, 8, mode == 2 ? 8 : 4);
        lstm_fused<<<grid, 512, 0, stream>>>(
            x  + (long)t1 * HW * 32,  hp1, B1, b1, c1, hn1,
            y1 + (long)t1 * HW * 64,
            y1 + (long)tm1 * HW * 64, hp2, B2, b2, c2, hn2,
            out + (long)tm1 * HW * 64,
            mode);
        if (mode != 1) { float* tmp = hp1; hp1 = hn1; hn1 = tmp; }
        if (mode != 0) { float* tmp = hp2; hp2 = hn2; hn2 = tmp; }
    }
}